// Round 8
// baseline (250.611 us; speedup 1.0000x reference)
//
#include <hip/hip_runtime.h>

#define NPTS 8192
#define DIM  128
#define NCLS 64
#define NT   64
#define NTILES (NT * (NT + 1) / 2)   // 2080 triangular tiles
#define NSPIN  256                   // last 256 tickets run the per-class loss
#define FEPS 1e-16f
#define L2E  1.442695041f

// ws layout (float elements). Kernels init all state (no host memset).
#define WS_S     0          // 8192 floats: S_i (sorted order)
#define WS_CNT   8192       // 64 ints
#define WS_LOSS  8256       // 1 float
#define WS_DONE  8257       // 1 uint (gemm ticket counter)
#define WS_SQ    8258       // 8192 floats (sorted order)
#define WS_OFFS  16450      // 64 ints: class start offsets
#define WS_DONE2 16514      // 1 uint (loss-phase completion counter)
#define WS_LABS  24642      // 8192 ints: sorted-order labels
#define WS_G16A  32836      // 16B aligned; 1MB fp8 = 262144 floats
#define WS_DP    294980     // fixed-stride dpair: class c at (c<<16), row stride 256

typedef float f32x4 __attribute__((ext_vector_type(4)));

__device__ inline float fast_sqrt(float x) {
    float r;
    asm("v_sqrt_f32 %0, %1" : "=v"(r) : "v"(x));
    return r;
}

// anti-diagonal tile decode: all tiles with distance d=jt-bt precede d+1.
__device__ inline void tile_decode(int p, int& bt, int& jt) {
    int d = (int)((129.0f - fast_sqrt((float)(16641 - 8 * p))) * 0.5f);
    if (d < 0) d = 0; if (d > 63) d = 63;
    while (d > 0 && (d * 64 - ((d * (d - 1)) >> 1)) > p) --d;
    while (((d + 1) * 64 - (((d + 1) * d) >> 1)) <= p) ++d;
    bt = p - (d * 64 - ((d * (d - 1)) >> 1));
    jt = bt + d;
}

// ---- node 1+2 fused: bucketing + fp8 prep, 128 blocks (2 per class) ----
__global__ void bucket_prep_kernel(const int* __restrict__ labels,
                                   const float* __restrict__ feat,
                                   int* __restrict__ cnt,
                                   int* __restrict__ offs,
                                   float* __restrict__ sq,
                                   unsigned char* __restrict__ G,
                                   float* __restrict__ S,
                                   int* __restrict__ labs,
                                   float* __restrict__ loss_sum,
                                   unsigned int* __restrict__ done,
                                   unsigned int* __restrict__ done2) {
    __shared__ int llab[NPTS];          // 32 KB
    __shared__ int plist[256];          // class point indices (n_c << 256)
    __shared__ int wsum[4], wless[4];
    const int tid = threadIdx.x;
    const int w = tid >> 6, lane = tid & 63;
    const int c = blockIdx.x >> 1, half = blockIdx.x & 1;

    {
        const uint4* L4 = (const uint4*)labels;
        uint4* S4 = (uint4*)llab;
#pragma unroll
        for (int k = 0; k < 8; ++k) S4[k * 256 + tid] = L4[k * 256 + tid];
    }
    if (blockIdx.x == 0 && tid == 0) { loss_sum[0] = 0.0f; done[0] = 0u; done2[0] = 0u; }
    __syncthreads();

    int ce = 0, clt = 0;
#pragma unroll
    for (int k = 0; k < 32; ++k) {
        int l = llab[tid + 256 * k];
        ce += (l == c) ? 1 : 0;
        clt += (l < c) ? 1 : 0;
    }
    int incl = ce;
#pragma unroll
    for (int o = 1; o < 64; o <<= 1) {
        int t1 = __shfl_up(incl, o, 64);
        if (lane >= o) incl += t1;
    }
    if (lane == 63) wsum[w] = incl;
    int t = clt;
#pragma unroll
    for (int o = 1; o < 64; o <<= 1) t += __shfl_xor(t, o, 64);
    if (lane == 0) wless[w] = t;
    __syncthreads();

    int wpre = 0;
#pragma unroll
    for (int ww = 0; ww < 4; ++ww) if (ww < w) wpre += wsum[ww];
    const int offc = wless[0] + wless[1] + wless[2] + wless[3];   // class base
    const int n = wsum[0] + wsum[1] + wsum[2] + wsum[3];          // class size

    int r = wpre + incl - ce;
#pragma unroll
    for (int k = 0; k < 32; ++k) {
        int idx = tid + 256 * k;
        if (llab[idx] == c) { plist[r] = idx; ++r; }
    }
    if (half == 0 && tid == 0) { cnt[c] = n; offs[c] = offc; }
    __syncthreads();   // plist visible

    const int mid = (n + 1) >> 1;
    const int lo = half ? mid : 0;
    const int hi = half ? n : mid;

    for (int m = lo + tid; m < hi; m += 256) { S[offc + m] = 0.0f; labs[offc + m] = c; }

    const int kl = lane & 31;
    const int rloc = lane >> 5;
    for (int base = lo; base < hi; base += 8) {
        int m = base + w * 2 + rloc;
        if (m < hi) {
            int i = plist[m];
            int sp = offc + m;
            float4 v = ((const float4*)(feat + (size_t)i * DIM))[kl];
            unsigned lo8 = (unsigned)__builtin_amdgcn_cvt_pk_fp8_f32(v.x, v.y, 0, false) & 0xffffu;
            unsigned hi8 = (unsigned)__builtin_amdgcn_cvt_pk_fp8_f32(v.z, v.w, 0, false);
            unsigned word = lo8 | (hi8 << 16);
            int tt = sp >> 7, mm = sp & 127;
            int cc = kl >> 1, pos = (kl & 1) * 4;
            *(unsigned*)&G[(size_t)tt * 16384 + cc * 1024 + mm * 8 + pos] = word;
            float s = v.x * v.x + v.y * v.y + v.z * v.z + v.w * v.w;
#pragma unroll
            for (int msk = 1; msk <= 16; msk <<= 1) s += __shfl_xor(s, msk, 64);
            if (kl == 0) sq[sp] = s;
        }
    }
}

// ---- node 3+4 fused: triangular N^2 pass + ticket-gated per-class loss ----
// Round-4 body (verified): heavy-first anti-diagonal order, LDS-staged G,
// no scan, hoisted reduces. NEW: after its tile, each block takes a ticket
// (device-scope atomic, post-fence). The last NSPIN tickets briefly spin
// until all 2080 tiles are done (deadlock-free: spinners are the LAST
// finishers, <=256 of 1024 resident slots; remaining blocks keep flowing
// through the other >=768 slots), acquire-fence, then run the per-class
// loss pass in-kernel. Removes the pairB launch + graph-node boundary.
__launch_bounds__(256, 4)
__global__ void gemm_S(const unsigned char* __restrict__ Gb,
                       const float* __restrict__ sq,
                       const int* __restrict__ labs,
                       const int* __restrict__ cnt,
                       const int* __restrict__ offs,
                       float* __restrict__ S,
                       float* __restrict__ dpair,
                       float* __restrict__ loss_sum,
                       unsigned int* __restrict__ done,
                       unsigned int* __restrict__ done2,
                       float* __restrict__ out) {
    int p = blockIdx.x;
    int bt, jt;
    tile_decode(p, bt, jt);

    __shared__ __align__(16) unsigned char ldsG[32768];   // A tile | B tile
    __shared__ float sqi[128], sqj[128];
    __shared__ int lli[128], llj[128];
    __shared__ int s_offs[NCLS];
    __shared__ float redf[4];
    __shared__ unsigned int s_ticket;

    const int tid = threadIdx.x;
    const int w = tid >> 6, lane = tid & 63;
    const int wr = w >> 1, wc = w & 1;
    const int q = lane >> 4, ml = lane & 15;
    const int ib = bt * 128, jb = jt * 128;
    const bool diag = (bt == jt);

    // async-stage both 16KB G tiles (diag stages same tile twice; uniform code)
    {
        const unsigned char* gA = Gb + (size_t)bt * 16384;
        const unsigned char* gB = Gb + (size_t)jt * 16384;
        const int wb = w << 10;          // wave-uniform LDS base within each 4KB step
        const int lb = lane << 4;
#pragma unroll
        for (int k = 0; k < 4; ++k) {
            __builtin_amdgcn_global_load_lds(
                (const __attribute__((address_space(1))) unsigned int*)(gA + (k << 12) + wb + lb),
                (__attribute__((address_space(3))) unsigned int*)(ldsG + (k << 12) + wb),
                16, 0, 0);
            __builtin_amdgcn_global_load_lds(
                (const __attribute__((address_space(1))) unsigned int*)(gB + (k << 12) + wb + lb),
                (__attribute__((address_space(3))) unsigned int*)(ldsG + 16384 + (k << 12) + wb),
                16, 0, 0);
        }
    }

    if (tid < 128) {
        sqi[tid] = sq[ib + tid]; lli[tid] = labs[ib + tid];
    } else {
        sqj[tid - 128] = sq[jb + tid - 128];
        llj[tid - 128] = labs[jb + tid - 128];
    }
    if (w == 0) s_offs[lane] = offs[lane];   // one load, no scan

    __syncthreads();   // covers staging (vmcnt) + sq/label/offs fills

    const bool boundary = diag || (lli[127] == llj[0]);

    const long* A8 = (const long*)ldsG;
    const long* B8 = (const long*)(ldsG + 16384);

    f32x4 acc[4][4];
#pragma unroll
    for (int a = 0; a < 4; ++a)
#pragma unroll
        for (int b = 0; b < 4; ++b) acc[a][b] = (f32x4){0.f, 0.f, 0.f, 0.f};

#pragma unroll
    for (int s = 0; s < 4; ++s) {
        long af[4], bf[4];
        int kbase = (s * 4 + q) * 128;
#pragma unroll
        for (int ii = 0; ii < 4; ++ii) af[ii] = A8[kbase + wr * 64 + ii * 16 + ml];
#pragma unroll
        for (int jj = 0; jj < 4; ++jj) bf[jj] = B8[kbase + wc * 64 + jj * 16 + ml];
#pragma unroll
        for (int ii = 0; ii < 4; ++ii)
#pragma unroll
            for (int jj = 0; jj < 4; ++jj)
                acc[ii][jj] = __builtin_amdgcn_mfma_f32_16x16x32_fp8_fp8(af[ii], bf[jj], acc[ii][jj], 0, 0, 0);
    }

    int cl[4]; float sj[4];
#pragma unroll
    for (int jj = 0; jj < 4; ++jj) {
        cl[jj] = wc * 64 + jj * 16 + ml;
        sj[jj] = sqj[cl[jj]];
    }
    float rs[4][4];
#pragma unroll
    for (int a = 0; a < 4; ++a)
#pragma unroll
        for (int r = 0; r < 4; ++r) rs[a][r] = 0.0f;
    float colsum[4] = {0.f, 0.f, 0.f, 0.f};

    if (!boundary) {
        // lean epilogue: no same-label pairs possible in this tile
#pragma unroll
        for (int ii = 0; ii < 4; ++ii) {
            int rl = wr * 64 + ii * 16 + q * 4;
            float si4[4];
#pragma unroll
            for (int r = 0; r < 4; ++r) si4[r] = sqi[rl + r];
#pragma unroll
            for (int jj = 0; jj < 4; ++jj)
#pragma unroll
                for (int r = 0; r < 4; ++r) {
                    float d2 = fmaf(-2.0f, acc[ii][jj][r], si4[r] + sj[jj]);
                    float dd = fast_sqrt(fmaxf(d2, FEPS));
                    float e = exp2f(fmaf(dd, -L2E, L2E));
                    rs[ii][r] += e;
                    colsum[jj] += e;
                }
        }
    } else {
        // full epilogue: label predicate + canonical dpair writes
        int lcj[4];
#pragma unroll
        for (int jj = 0; jj < 4; ++jj) lcj[jj] = llj[cl[jj]];
#pragma unroll
        for (int ii = 0; ii < 4; ++ii) {
            int rl = wr * 64 + ii * 16 + q * 4;
            int lri[4]; float si4[4];
#pragma unroll
            for (int r = 0; r < 4; ++r) { lri[r] = lli[rl + r]; si4[r] = sqi[rl + r]; }
#pragma unroll
            for (int jj = 0; jj < 4; ++jj)
#pragma unroll
                for (int r = 0; r < 4; ++r) {
                    float d2 = fmaf(-2.0f, acc[ii][jj][r], si4[r] + sj[jj]);
                    float dd = fast_sqrt(fmaxf(d2, FEPS));
                    float e = exp2f(fmaf(dd, -L2E, L2E));
                    bool same = (lri[r] == lcj[jj]);
                    float ep = same ? 0.0f : e;
                    rs[ii][r] += ep;
                    colsum[jj] += ep;
                    if (same) {
                        int c2 = lri[r];
                        int offv = s_offs[c2];
                        int ra = ib + rl + r - offv;
                        int rb = jb + cl[jj] - offv;
                        if (ra < rb)
                            dpair[(c2 << 16) + (ra << 8) + rb] = dd;  // fixed stride 256
                    }
                }
        }
    }

    // hoisted reduces: 16 independent depth-4 chains, pipelined
#pragma unroll
    for (int m = 1; m < 16; m <<= 1)
#pragma unroll
        for (int ii = 0; ii < 4; ++ii)
#pragma unroll
            for (int r = 0; r < 4; ++r) rs[ii][r] += __shfl_xor(rs[ii][r], m, 64);
    if (ml == 0) {
#pragma unroll
        for (int ii = 0; ii < 4; ++ii) {
            int rl = wr * 64 + ii * 16 + q * 4;
#pragma unroll
            for (int r = 0; r < 4; ++r) atomicAdd(&S[ib + rl + r], rs[ii][r]);
        }
    }
    if (!diag) {
#pragma unroll
        for (int m = 16; m < 64; m <<= 1)
#pragma unroll
            for (int jj = 0; jj < 4; ++jj) colsum[jj] += __shfl_xor(colsum[jj], m, 64);
        if (q == 0) {
#pragma unroll
            for (int jj = 0; jj < 4; ++jj)
                atomicAdd(&S[jb + cl[jj]], colsum[jj]);
        }
    }

    // ---- ticket: publish this tile's writes, then maybe run the loss pass ----
    __threadfence();                               // release S + dpair (device scope)
    if (tid == 0) s_ticket = atomicAdd(done, 1u);
    __syncthreads();
    const unsigned int ticket = s_ticket;
    if (ticket < (unsigned)(NTILES - NSPIN)) return;

    // ---- fused node 4: per-(class,quarter) loss (last NSPIN finishers) ----
    const int sp = (int)ticket - (NTILES - NSPIN);
    const int c = sp >> 2, q4 = sp & 3;

    if (tid == 0) {
        while (atomicAdd(done, 0u) < (unsigned)NTILES) __builtin_amdgcn_s_sleep(2);
    }
    __syncthreads();
    __threadfence();                               // acquire: invalidate stale L1/L2

    const int n = cnt[c];
    const int off = offs[c];
    const float* dbase = dpair + (c << 16);
    float* Sg = (float*)ldsG;                      // reuse tile LDS

    for (int m_ = tid; m_ < n; m_ += 256) Sg[m_] = S[off + m_];   // contiguous
    __syncthreads();

    float total = 0.f;
    for (int a = q4 * 4 + w; a < n; a += 16) {     // 16 row-streams across 4 tickets
        float Sa = Sg[a];
        const float* drow = dbase + (a << 8);
        for (int bb = lane; bb < n; bb += 64) {
            if (bb > a) {
                float J = __logf(Sa + Sg[bb]) + drow[bb];   // coalesced upper-tri read
                float h = fmaxf(J, 0.0f);
                total += 2.0f * h * h;                      // symmetry
            }
        }
        if (lane == 0) {                                    // diagonal: d = sqrt(EPS)
            float J = __logf(2.0f * Sa) + 1e-8f;
            float h = fmaxf(J, 0.0f);
            total += h * h;
        }
    }
#pragma unroll
    for (int off2 = 32; off2 > 0; off2 >>= 1) total += __shfl_down(total, off2, 64);
    if (lane == 0) redf[w] = total;

    int tot2 = 0;
    if (w == 0) {                                  // sum n_c^2 (writeout divisor)
        int v = cnt[lane];
        tot2 = v * v;
#pragma unroll
        for (int o = 1; o < 64; o <<= 1) tot2 += __shfl_xor(tot2, o, 64);
    }
    __syncthreads();
    if (tid == 0) {
        atomicAdd(loss_sum, redf[0] + redf[1] + redf[2] + redf[3]);
        __threadfence();
        unsigned int t2 = atomicAdd(done2, 1u);
        if (t2 == NSPIN - 1) {
            float tot = atomicAdd(loss_sum, 0.0f);
            out[0] = tot / (2.0f * (float)tot2);
        }
    }
}

extern "C" void kernel_launch(void* const* d_in, const int* in_sizes, int n_in,
                              void* d_out, int out_size, void* d_ws, size_t ws_size,
                              hipStream_t stream) {
    const float* feat = (const float*)d_in[0];
    const int* labels = (const int*)d_in[1];

    float* ws = (float*)d_ws;
    float* S = ws + WS_S;
    int* cnt = (int*)(ws + WS_CNT);
    float* loss_sum = ws + WS_LOSS;
    unsigned int* done = (unsigned int*)(ws + WS_DONE);
    float* sq = ws + WS_SQ;
    int* offs = (int*)(ws + WS_OFFS);
    unsigned int* done2 = (unsigned int*)(ws + WS_DONE2);
    int* labs = (int*)(ws + WS_LABS);
    unsigned char* G8 = (unsigned char*)(ws + WS_G16A);
    float* dpair = ws + WS_DP;
    float* outp = (float*)d_out;

    bucket_prep_kernel<<<NCLS * 2, 256, 0, stream>>>(labels, feat, cnt, offs, sq, G8,
                                                     S, labs, loss_sum, done, done2); // node 1+2
    gemm_S<<<NTILES, 256, 0, stream>>>(G8, sq, labs, cnt, offs, S, dpair,
                                       loss_sum, done, done2, outp);                  // node 3+4
}

// Round 9
// 100.887 us; speedup vs baseline: 2.4841x; 2.4841x over previous
//
#include <hip/hip_runtime.h>

#define NPTS 8192
#define DIM  128
#define NCLS 64
#define NT   64
#define NTILES (NT * (NT + 1) / 2)   // 2080 triangular tiles
#define FEPS 1e-16f
#define L2E  1.442695041f

// ws layout (float elements). Kernels init all state (no host memset).
#define WS_S     0          // 8192 floats: S_i (sorted order)
#define WS_CNT   8192       // 64 ints
#define WS_LOSS  8256       // 1 float
#define WS_DONE  8257       // 1 uint
#define WS_SQ    8258       // 8192 floats (sorted order)
#define WS_SPOS  16450      // 8192 ints: i -> sorted position
#define WS_LABS  24642      // 8192 ints: sorted-order labels
#define WS_G16A  32836      // 16B aligned (32836*4=131344=16*8209); 1MB fp8 = 262144 floats
#define WS_DP    294980     // = 32836 + 262144, AFTER G. ~1.1M floats upper-tri distances

typedef float f32x4 __attribute__((ext_vector_type(4)));

__device__ inline float fast_sqrt(float x) {
    float r;
    asm("v_sqrt_f32 %0, %1" : "=v"(r) : "v"(x));
    return r;
}

// ---- node 1: bucketing -> sorted positions (64 blocks, LDS-local, no cross-block deps) ----
__global__ void bucket_kernel(const int* __restrict__ labels,
                              int* __restrict__ cnt,
                              int* __restrict__ spos,
                              float* __restrict__ loss_sum,
                              unsigned int* __restrict__ done) {
    __shared__ int llab[NPTS];          // 32 KB
    __shared__ int wsum[4], wless[4];
    const int tid = threadIdx.x;
    const int w = tid >> 6, lane = tid & 63;
    const int c = blockIdx.x;

    {
        const uint4* L4 = (const uint4*)labels;
        uint4* S4 = (uint4*)llab;
#pragma unroll
        for (int k = 0; k < 8; ++k) S4[k * 256 + tid] = L4[k * 256 + tid];
    }
    if (c == 0 && tid == 0) { loss_sum[0] = 0.0f; done[0] = 0u; }
    __syncthreads();

    // lane-consecutive chunks (bank-conflict-free)
    int ce = 0, clt = 0;
#pragma unroll
    for (int k = 0; k < 32; ++k) {
        int l = llab[tid + 256 * k];
        ce += (l == c) ? 1 : 0;
        clt += (l < c) ? 1 : 0;
    }
    int incl = ce;
#pragma unroll
    for (int o = 1; o < 64; o <<= 1) {
        int t1 = __shfl_up(incl, o, 64);
        if (lane >= o) incl += t1;
    }
    if (lane == 63) wsum[w] = incl;
    int t = clt;
#pragma unroll
    for (int o = 1; o < 64; o <<= 1) t += __shfl_xor(t, o, 64);
    if (lane == 0) wless[w] = t;
    __syncthreads();

    int wpre = 0;
#pragma unroll
    for (int ww = 0; ww < 4; ++ww) if (ww < w) wpre += wsum[ww];
    const int offc = wless[0] + wless[1] + wless[2] + wless[3];

    int r = offc + wpre + incl - ce;
#pragma unroll
    for (int k = 0; k < 32; ++k) {
        int idx = tid + 256 * k;
        if (llab[idx] == c) { spos[idx] = r; ++r; }
    }
    if (tid == 0) cnt[c] = wsum[0] + wsum[1] + wsum[2] + wsum[3];
}

// ---- node 2: prep into SORTED order (1024 blocks) ----
// G layout (BYTE units, fp8 e4m3): tile t=sp>>7 (16384 B) | chunk c=k>>3 (1024 B)
//                                  | m=sp&127 (8 B) | k&7
__global__ void prep_kernel(const float* __restrict__ feat,
                            const int* __restrict__ labels,
                            const int* __restrict__ spos,
                            float* __restrict__ sq,
                            unsigned char* __restrict__ G,
                            float* __restrict__ S,
                            int* __restrict__ labs) {
    const int tid = threadIdx.x;
    const int w = tid >> 6, lane = tid & 63;
    const int kl = lane & 31;
    const int rloc = lane >> 5;
    int i = blockIdx.x * 8 + w * 2 + rloc;
    int sp = spos[i];
    float4 v = ((const float4*)(feat + (size_t)i * DIM))[kl];
    unsigned lo = (unsigned)__builtin_amdgcn_cvt_pk_fp8_f32(v.x, v.y, 0, false) & 0xffffu;
    unsigned hi = (unsigned)__builtin_amdgcn_cvt_pk_fp8_f32(v.z, v.w, 0, false);
    unsigned word = lo | (hi << 16);
    int t = sp >> 7, m = sp & 127;
    int c = kl >> 1, pos = (kl & 1) * 4;
    *(unsigned*)&G[(size_t)t * 16384 + c * 1024 + m * 8 + pos] = word;
    float s = v.x * v.x + v.y * v.y + v.z * v.z + v.w * v.w;
#pragma unroll
    for (int msk = 1; msk <= 16; msk <<= 1) s += __shfl_xor(s, msk, 64);
    if (kl == 0) { sq[sp] = s; labs[sp] = labels[i]; }
    if (tid < 8) S[blockIdx.x * 8 + tid] = 0.0f;
}

// ---- node 3: triangular N^2 pass (verified best: round-1 structure) ----
//  * heavy-first (anti-diagonal) tile order: the ~127 full-epilogue tiles land
//    on distinct CUs in the first dispatch round
//  * G tiles staged to LDS via global_load_lds; one barrier
//  * exp(1-d) as exp2(fma(d,-log2e,log2e))
__launch_bounds__(256, 4)
__global__ void gemm_S(const unsigned char* __restrict__ Gb,
                       const float* __restrict__ sq,
                       const int* __restrict__ labs,
                       const int* __restrict__ cnt,
                       float* __restrict__ S,
                       float* __restrict__ dpair) {
    int p = blockIdx.x;
    // anti-diagonal order: all tiles with distance d = jt-bt come before d+1.
    // cum(d) = 64d - d(d-1)/2 tiles precede distance d. Solve then repair.
    int d = (int)((129.0f - fast_sqrt((float)(16641 - 8 * p))) * 0.5f);
    if (d < 0) d = 0; if (d > 63) d = 63;
    while (d > 0 && (d * 64 - ((d * (d - 1)) >> 1)) > p) --d;
    while (((d + 1) * 64 - (((d + 1) * d) >> 1)) <= p) ++d;   // cum(64)=2080 > p always
    const int bt = p - (d * 64 - ((d * (d - 1)) >> 1));
    const int jt = bt + d;

    __shared__ __align__(16) unsigned char ldsG[32768];   // A tile | B tile
    __shared__ float sqi[128], sqj[128];
    __shared__ int lli[128], llj[128];
    __shared__ int s_cnt[NCLS], s_offs[NCLS], s_poff[NCLS];

    const int tid = threadIdx.x;
    const int w = tid >> 6, lane = tid & 63;
    const int wr = w >> 1, wc = w & 1;
    const int q = lane >> 4, ml = lane & 15;
    const int ib = bt * 128, jb = jt * 128;
    const bool diag = (bt == jt);

    // async-stage both 16KB G tiles (diag stages same tile twice; uniform code)
    {
        const unsigned char* gA = Gb + (size_t)bt * 16384;
        const unsigned char* gB = Gb + (size_t)jt * 16384;
        const int wb = w << 10;          // wave-uniform LDS base within each 4KB step
        const int lb = lane << 4;
#pragma unroll
        for (int k = 0; k < 4; ++k) {
            __builtin_amdgcn_global_load_lds(
                (const __attribute__((address_space(1))) unsigned int*)(gA + (k << 12) + wb + lb),
                (__attribute__((address_space(3))) unsigned int*)(ldsG + (k << 12) + wb),
                16, 0, 0);
            __builtin_amdgcn_global_load_lds(
                (const __attribute__((address_space(1))) unsigned int*)(gB + (k << 12) + wb + lb),
                (__attribute__((address_space(3))) unsigned int*)(ldsG + 16384 + (k << 12) + wb),
                16, 0, 0);
        }
    }

    if (tid < 128) {
        int i = ib + tid;
        sqi[tid] = sq[i]; lli[tid] = labs[i];
    } else {
        int j = jb + tid - 128;
        sqj[tid - 128] = sq[j]; llj[tid - 128] = labs[j];
    }
    if (w == 0) {                        // wave 0: scan cnt -> offs, poff
        int v = cnt[lane];
        s_cnt[lane] = v;
        int v2 = v * v, s1 = v, s2 = v2;
#pragma unroll
        for (int o = 1; o < 64; o <<= 1) {
            int t1 = __shfl_up(s1, o, 64);
            int t2 = __shfl_up(s2, o, 64);
            if (lane >= o) { s1 += t1; s2 += t2; }
        }
        s_offs[lane] = s1 - v;
        s_poff[lane] = s2 - v2;
    }
    __syncthreads();   // covers staging (vmcnt) + sq/label fills + scan

    const bool boundary = diag || (lli[127] == llj[0]);   // sorted: overlap iff edges match

    const long* A8 = (const long*)ldsG;
    const long* B8 = (const long*)(ldsG + 16384);

    f32x4 acc[4][4];
#pragma unroll
    for (int a = 0; a < 4; ++a)
#pragma unroll
        for (int b = 0; b < 4; ++b) acc[a][b] = (f32x4){0.f, 0.f, 0.f, 0.f};

#pragma unroll
    for (int s = 0; s < 4; ++s) {
        long af[4], bf[4];
        int kbase = (s * 4 + q) * 128;
#pragma unroll
        for (int ii = 0; ii < 4; ++ii) af[ii] = A8[kbase + wr * 64 + ii * 16 + ml];
#pragma unroll
        for (int jj = 0; jj < 4; ++jj) bf[jj] = B8[kbase + wc * 64 + jj * 16 + ml];
#pragma unroll
        for (int ii = 0; ii < 4; ++ii)
#pragma unroll
            for (int jj = 0; jj < 4; ++jj)
                acc[ii][jj] = __builtin_amdgcn_mfma_f32_16x16x32_fp8_fp8(af[ii], bf[jj], acc[ii][jj], 0, 0, 0);
    }

    int cl[4]; float sj[4];
#pragma unroll
    for (int jj = 0; jj < 4; ++jj) {
        cl[jj] = wc * 64 + jj * 16 + ml;
        sj[jj] = sqj[cl[jj]];
    }
    float colsum[4] = {0.f, 0.f, 0.f, 0.f};

    if (!boundary) {
        // ---- lean epilogue: no same-label pairs possible in this tile ----
#pragma unroll
        for (int ii = 0; ii < 4; ++ii) {
            int rl = wr * 64 + ii * 16 + q * 4;
            float si4[4];
#pragma unroll
            for (int r = 0; r < 4; ++r) si4[r] = sqi[rl + r];
            float rs[4] = {0.f, 0.f, 0.f, 0.f};
#pragma unroll
            for (int jj = 0; jj < 4; ++jj)
#pragma unroll
                for (int r = 0; r < 4; ++r) {
                    float d2 = fmaf(-2.0f, acc[ii][jj][r], si4[r] + sj[jj]);
                    float dd = fast_sqrt(fmaxf(d2, FEPS));
                    float e = exp2f(fmaf(dd, -L2E, L2E));
                    rs[r] += e;
                    colsum[jj] += e;
                }
#pragma unroll
            for (int m = 1; m < 16; m <<= 1)
#pragma unroll
                for (int r = 0; r < 4; ++r) rs[r] += __shfl_xor(rs[r], m, 64);
            if (ml == 0) {
#pragma unroll
                for (int r = 0; r < 4; ++r) atomicAdd(&S[ib + rl + r], rs[r]);
            }
        }
        // lean tiles are never diagonal -> always accumulate column sums
#pragma unroll
        for (int m = 16; m < 64; m <<= 1)
#pragma unroll
            for (int jj = 0; jj < 4; ++jj) colsum[jj] += __shfl_xor(colsum[jj], m, 64);
        if (q == 0) {
#pragma unroll
            for (int jj = 0; jj < 4; ++jj)
                atomicAdd(&S[jb + cl[jj]], colsum[jj]);
        }
    } else {
        // ---- full epilogue: label predicate + canonical dpair writes ----
        int lcj[4];
#pragma unroll
        for (int jj = 0; jj < 4; ++jj) lcj[jj] = llj[cl[jj]];
#pragma unroll
        for (int ii = 0; ii < 4; ++ii) {
            int rl = wr * 64 + ii * 16 + q * 4;
            int lri[4]; float si4[4];
#pragma unroll
            for (int r = 0; r < 4; ++r) { lri[r] = lli[rl + r]; si4[r] = sqi[rl + r]; }
            float rs[4] = {0.f, 0.f, 0.f, 0.f};
#pragma unroll
            for (int jj = 0; jj < 4; ++jj)
#pragma unroll
                for (int r = 0; r < 4; ++r) {
                    float d2 = fmaf(-2.0f, acc[ii][jj][r], si4[r] + sj[jj]);
                    float dd = fast_sqrt(fmaxf(d2, FEPS));
                    float e = exp2f(fmaf(dd, -L2E, L2E));
                    bool same = (lri[r] == lcj[jj]);
                    float ep = same ? 0.0f : e;
                    rs[r] += ep;
                    colsum[jj] += ep;
                    if (same) {
                        int c2 = lri[r];
                        int n = s_cnt[c2], base = s_poff[c2], off = s_offs[c2];
                        int ra = ib + rl + r - off;
                        int rb = jb + cl[jj] - off;
                        if (ra < rb)
                            dpair[base + ra * n + rb] = dd;  // upper-tri canonical,
                    }                                        // lane-contiguous in rb
                }
#pragma unroll
            for (int m = 1; m < 16; m <<= 1)
#pragma unroll
                for (int r = 0; r < 4; ++r) rs[r] += __shfl_xor(rs[r], m, 64);
            if (ml == 0) {
#pragma unroll
                for (int r = 0; r < 4; ++r) atomicAdd(&S[ib + rl + r], rs[r]);
            }
        }
        if (!diag) {
#pragma unroll
            for (int m = 16; m < 64; m <<= 1)
#pragma unroll
                for (int jj = 0; jj < 4; ++jj) colsum[jj] += __shfl_xor(colsum[jj], m, 64);
            if (q == 0) {
#pragma unroll
                for (int jj = 0; jj < 4; ++jj)
                    atomicAdd(&S[jb + cl[jj]], colsum[jj]);
            }
        }
    }
}

// ---- node 4: per-class loss, 4 blocks/class, contiguous S + coalesced dpair rows ----
__global__ void pairB_kernel(const float* __restrict__ S,
                             const int* __restrict__ cnt,
                             const float* __restrict__ dpair,
                             float* __restrict__ loss_sum,
                             unsigned int* __restrict__ done,
                             float* __restrict__ out) {
    __shared__ float Sg[256];
    __shared__ float redf[4];
    __shared__ int s_pb, s_n, s_off, s_tot;
    const int tid = threadIdx.x;
    const int w = tid >> 6, lane = tid & 63;
    const int c = blockIdx.x >> 2, q4 = blockIdx.x & 3;

    if (w == 0) {                        // wave 0: scan cnt -> off, poff
        int v = cnt[lane];
        int v2 = v * v, s1 = v, s2 = v2;
#pragma unroll
        for (int o = 1; o < 64; o <<= 1) {
            int t1 = __shfl_up(s1, o, 64);
            int t2 = __shfl_up(s2, o, 64);
            if (lane >= o) { s1 += t1; s2 += t2; }
        }
        if (lane == c) { s_pb = s2 - v2; s_off = s1 - v; s_n = v; }
        if (lane == 63) s_tot = s2;
    }
    __syncthreads();
    const int n = s_n, pb = s_pb, off = s_off;

    for (int m_ = tid; m_ < n; m_ += 256) Sg[m_] = S[off + m_];   // contiguous
    __syncthreads();

    float total = 0.f;
    for (int a = q4 * 4 + w; a < n; a += 16) {   // 16 row-streams across 4 blocks
        float Sa = Sg[a];
        const float* drow = dpair + pb + a * n;
        for (int b = lane; b < n; b += 64) {
            if (b > a) {
                float J = __logf(Sa + Sg[b]) + drow[b];   // coalesced upper-tri read
                float h = fmaxf(J, 0.0f);
                total += 2.0f * h * h;                    // symmetry
            }
        }
        if (lane == 0) {                                  // diagonal: d = sqrt(EPS)
            float J = __logf(2.0f * Sa) + 1e-8f;
            float h = fmaxf(J, 0.0f);
            total += h * h;
        }
    }
#pragma unroll
    for (int off2 = 32; off2 > 0; off2 >>= 1) total += __shfl_down(total, off2, 64);
    if (lane == 0) redf[w] = total;
    __syncthreads();
    if (tid == 0) {
        atomicAdd(loss_sum, redf[0] + redf[1] + redf[2] + redf[3]);
        __threadfence();
        unsigned int t = atomicAdd(done, 1u);
        if (t == gridDim.x - 1) {
            float tot = atomicAdd(loss_sum, 0.0f);
            out[0] = tot / (2.0f * (float)s_tot);
        }
    }
}

extern "C" void kernel_launch(void* const* d_in, const int* in_sizes, int n_in,
                              void* d_out, int out_size, void* d_ws, size_t ws_size,
                              hipStream_t stream) {
    const float* feat = (const float*)d_in[0];
    const int* labels = (const int*)d_in[1];

    float* ws = (float*)d_ws;
    float* S = ws + WS_S;
    int* cnt = (int*)(ws + WS_CNT);
    float* loss_sum = ws + WS_LOSS;
    unsigned int* done = (unsigned int*)(ws + WS_DONE);
    float* sq = ws + WS_SQ;
    int* spos = (int*)(ws + WS_SPOS);
    int* labs = (int*)(ws + WS_LABS);
    unsigned char* G8 = (unsigned char*)(ws + WS_G16A);
    float* dpair = ws + WS_DP;
    float* outp = (float*)d_out;

    bucket_kernel<<<NCLS, 256, 0, stream>>>(labels, cnt, spos, loss_sum, done);   // node 1
    prep_kernel<<<NPTS / 8, 256, 0, stream>>>(feat, labels, spos, sq, G8, S, labs); // node 2
    gemm_S<<<NTILES, 256, 0, stream>>>(G8, sq, labs, cnt, S, dpair);              // node 3
    pairB_kernel<<<NCLS * 4, 256, 0, stream>>>(S, cnt, dpair, loss_sum, done, outp); // node 4
}